// Round 2
// baseline (469.414 us; speedup 1.0000x reference)
//
#include <hip/hip_runtime.h>

#define NROWS 262144
#define DDIM  256
#define KREF  32

// DPP butterfly add within 16-lane rows: all 16 lanes end with the 16-sum.
template <int CTRL>
__device__ __forceinline__ float dpp_xadd(float v) {
    int r = __builtin_amdgcn_update_dpp(0, __float_as_int(v), CTRL, 0xF, 0xF, true);
    return v + __int_as_float(r);
}
__device__ __forceinline__ float reduce16(float s) {
    s = dpp_xadd<0xB1>(s);   // quad_perm [1,0,3,2]  = xor 1
    s = dpp_xadd<0x4E>(s);   // quad_perm [2,3,0,1]  = xor 2
    s = dpp_xadd<0x141>(s);  // row_half_mirror      = xor 7
    s = dpp_xadd<0x140>(s);  // row_mirror           = xor 15
    return s;
}

__global__ void beta_kernel(const float* __restrict__ q, float* __restrict__ beta) {
    int k = threadIdx.x;
    if (k < KREF) {
        const float4* row = (const float4*)(q + k * DDIM);
        float s0 = 0.f, s1 = 0.f, s2 = 0.f, s3 = 0.f;
        #pragma unroll 8
        for (int i = 0; i < DDIM / 4; ++i) {
            float4 v = row[i];
            s0 += v.x * v.x; s1 += v.y * v.y;
            s2 += v.z * v.z; s3 += v.w * v.w;
        }
        beta[k] = 2.0f / ((s0 + s1) + (s2 + s3));
    }
}

__global__ __launch_bounds__(256)
void hh_kernel(const float* __restrict__ X, const float* __restrict__ Q,
               const float* __restrict__ beta, float* __restrict__ out) {
    __shared__ float q_lds[KREF * DDIM];   // 32 KB
    __shared__ float beta_lds[KREF];

    const int tid = threadIdx.x;

    // Stage all q vectors to LDS (coalesced float4)
    {
        const float4* qsrc = (const float4*)Q;
        float4* qdst = (float4*)q_lds;
        #pragma unroll
        for (int i = 0; i < (KREF * DDIM / 4) / 256; ++i)
            qdst[tid + i * 256] = qsrc[tid + i * 256];
        if (tid < KREF) beta_lds[tid] = beta[tid];
    }
    __syncthreads();

    const int wave = tid >> 6;
    const int lane = tid & 63;
    const int t = lane & 15;        // position within 16-lane row group
    const int g = lane >> 4;        // row group 0..3

    // This wave handles rows rbase + {0..15}; lane handles rowsets j: rbase + j*4 + g
    const int rbase = blockIdx.x * 64 + wave * 16;
    const int row0  = rbase + g;

    // Fragment: columns c*64 + 4t .. 4t+3 for c = 0..3 (16 floats per lane per row)
    float4 x[4][4];   // [rowset][c]
    #pragma unroll
    for (int j = 0; j < 4; ++j) {
        const float* rp = X + (size_t)(row0 + j * 4) * DDIM + 4 * t;
        #pragma unroll
        for (int c = 0; c < 4; ++c)
            x[j][c] = *(const float4*)(rp + c * 64);
    }

    for (int k = 0; k < KREF; ++k) {
        const float* qk = q_lds + k * DDIM + 4 * t;
        float4 qf[4];
        #pragma unroll
        for (int c = 0; c < 4; ++c)
            qf[c] = *(const float4*)(qk + c * 64);
        const float bk = beta_lds[k];

        #pragma unroll
        for (int j = 0; j < 4; ++j) {
            float s = 0.f;
            #pragma unroll
            for (int c = 0; c < 4; ++c) {
                s += x[j][c].x * qf[c].x;
                s += x[j][c].y * qf[c].y;
                s += x[j][c].z * qf[c].z;
                s += x[j][c].w * qf[c].w;
            }
            s = reduce16(s);
            const float cb = s * bk;
            #pragma unroll
            for (int c = 0; c < 4; ++c) {
                x[j][c].x -= cb * qf[c].x;
                x[j][c].y -= cb * qf[c].y;
                x[j][c].z -= cb * qf[c].z;
                x[j][c].w -= cb * qf[c].w;
            }
        }
    }

    // Store result rows
    #pragma unroll
    for (int j = 0; j < 4; ++j) {
        float* rp = out + (size_t)(row0 + j * 4) * DDIM + 4 * t;
        #pragma unroll
        for (int c = 0; c < 4; ++c)
            *(float4*)(rp + c * 64) = x[j][c];
    }

    // logabsdet = zeros(N), appended after N*D outputs
    if (tid < 64)
        out[(size_t)NROWS * DDIM + blockIdx.x * 64 + tid] = 0.0f;
}

extern "C" void kernel_launch(void* const* d_in, const int* in_sizes, int n_in,
                              void* d_out, int out_size, void* d_ws, size_t ws_size,
                              hipStream_t stream) {
    const float* X = (const float*)d_in[0];   // [N, D] fp32
    const float* Q = (const float*)d_in[1];   // [K, D] fp32
    float* out  = (float*)d_out;              // [N*D + N] fp32
    float* beta = (float*)d_ws;               // K floats scratch

    beta_kernel<<<1, 64, 0, stream>>>(Q, beta);
    hh_kernel<<<NROWS / 64, 256, 0, stream>>>(X, Q, beta, out);
}